// Round 2
// baseline (508.166 us; speedup 1.0000x reference)
//
#include <hip/hip_runtime.h>
#include <math.h>

#define N_NODES 100000
#define N_EDGES 800000
#define D_IN    64
#define HC      128   // H*C
#define CAP     48    // max in-degree slots (Poisson(8): P(>48) ~ 0)

// tanh-approx gelu (jax.nn.gelu default approximate=True)
__device__ __forceinline__ float gelu_f(float x) {
    float x3 = x * x * x;
    float y  = 0.7978845608028654f * (x + 0.044715f * x3);
    float t = 1.0f - 2.0f / (__expf(2.0f * y) + 1.0f);
    return 0.5f * x * (1.0f + t);
}

// sum across a 16-lane row via DPP row_ror (pure VALU, no ds_swizzle)
__device__ __forceinline__ float red16(float x) {
    x += __int_as_float(__builtin_amdgcn_mov_dpp(__float_as_int(x), 0x128, 0xF, 0xF, true)); // ror:8
    x += __int_as_float(__builtin_amdgcn_mov_dpp(__float_as_int(x), 0x124, 0xF, 0xF, true)); // ror:4
    x += __int_as_float(__builtin_amdgcn_mov_dpp(__float_as_int(x), 0x122, 0xF, 0xF, true)); // ror:2
    x += __int_as_float(__builtin_amdgcn_mov_dpp(__float_as_int(x), 0x121, 0xF, 0xF, true)); // ror:1
    return x;
}

// ---------------- CSR-by-capacity scatter (once; shared by both layers) ----
__global__ void scatter_kernel(const int* __restrict__ edges,
                               int* __restrict__ cnt, int* __restrict__ tbl) {
    int e = blockIdx.x * blockDim.x + threadIdx.x;
    if (e >= N_EDGES) return;
    int s = edges[e];            // src row
    int d = edges[N_EDGES + e];  // dst row
    int slot = atomicAdd(&cnt[d], 1);
    if (slot < CAP) tbl[d * CAP + slot] = s;
}

// ---------------- xl/xr GEMM: [N,64] @ [64,128] + b -------------------------
// Wave = 64 nodes (1/lane) x 64 channels; block = 4 waves sharing one staged
// 64-node X tile. Chunks: w0->XL[0:64], w1->XL[64:128], w2->XR[0:64],
// w3->XR[64:128]. W/b stay wave-uniform (readfirstlane) -> scalar s_load
// stream, FMAs are v_fmac v,s,v. x via one ds_read_b128 per 4 k-steps.
// 6252 waves (~6/SIMD), short bodies -> latency hidden (was 3128 long waves,
// VALUBusy 18%).
__global__ __launch_bounds__(256, 4) void gemm_kernel(
    const float* __restrict__ X,
    const float* __restrict__ Wl, const float* __restrict__ bl,
    const float* __restrict__ Wr, const float* __restrict__ br,
    float* __restrict__ XL, float* __restrict__ XR) {
    __shared__ float xs[64 * 68];          // 64 rows, pad to 68 floats
    const int t  = threadIdx.x;
    const int n0 = blockIdx.x * 64;

    // stage 64 rows x 16 float4 = 1024 float4, 4 per thread, coalesced
    #pragma unroll
    for (int p = 0; p < 4; ++p) {
        int f   = p * 256 + t;
        int row = f >> 4, q = f & 15;
        int n   = n0 + row;
        float4 val = make_float4(0.0f, 0.0f, 0.0f, 0.0f);
        if (n < N_NODES) val = *(const float4*)(X + (size_t)n * D_IN + 4 * q);
        *(float4*)(&xs[row * 68 + 4 * q]) = val;
    }
    __syncthreads();

    const int lane = t & 63;
    const int w    = __builtin_amdgcn_readfirstlane(t >> 6);  // wave id 0..3
    const int sel  = w >> 1;
    const int cc0  = (w & 1) * 64;
    const float* __restrict__ Wp = (sel ? Wr : Wl) + cc0;
    const float* __restrict__ bp = (sel ? br : bl) + cc0;
    float*       __restrict__ OUT = sel ? XR : XL;

    float acc[64];
    #pragma unroll
    for (int i = 0; i < 64; ++i) acc[i] = bp[i];              // s_load

    const float* xrow = &xs[lane * 68];
    #pragma unroll 1
    for (int kq = 0; kq < 16; ++kq) {                         // rolled: fits I$
        float4 xk = *(const float4*)(xrow + 4 * kq);          // ds_read_b128
        #pragma unroll
        for (int j = 0; j < 4; ++j) {
            const float* wk = Wp + (4 * kq + j) * HC;         // uniform -> s_load
            float xj = j == 0 ? xk.x : j == 1 ? xk.y : j == 2 ? xk.z : xk.w;
            #pragma unroll
            for (int i = 0; i < 64; ++i)
                acc[i] = fmaf(xj, wk[i], acc[i]);             // v_fmac v,s,v
        }
    }

    const int n = n0 + lane;
    if (n < N_NODES) {
        float* o = &OUT[(size_t)n * HC + cc0];
        #pragma unroll
        for (int q = 0; q < 16; ++q)
            *(float4*)(o + 4 * q) = make_float4(acc[4*q], acc[4*q+1],
                                                acc[4*q+2], acc[4*q+3]);
    }
}

// ---------------- wave-per-node aggregation: 2 edges/iter, 4 ch/lane --------
// lanes 0-31: edge i, lanes 32-63: edge i+1. Within a 32-lane half:
// lanes 0-15 head0, 16-31 head1; lane li handles channels 4*li..4*li+3.
// Score reduce = 4 DPP row_ror adds (no DS ops). Softmax uses a FIXED shift
// m0 = e_self (same alpha ratios as running-max; e - e_self is O(+-15) here,
// safe in fp32) -> accumulation is associative: 1 exp + 4 fma per half.
__global__ __launch_bounds__(256) void aggregate_kernel(
    const float* __restrict__ XL, const float* __restrict__ XR,
    const int* __restrict__ cnt, const int* __restrict__ tbl,
    const float* __restrict__ att, const float* __restrict__ bias,
    float* __restrict__ Y, int applyGelu) {
    const int v = (blockIdx.x * blockDim.x + threadIdx.x) >> 6;
    const int lane = threadIdx.x & 63;
    if (v >= N_NODES) return;
    const int half = lane >> 5;          // which edge of the pair
    const int li   = lane & 15;
    const int hc   = ((lane >> 4) & 1) * 64 + 4 * li;

    const float4 a4  = *(const float4*)(att + hc);
    const float4 xr4 = *(const float4*)(XR + (size_t)v * HC + hc);
    const float4 xl4 = *(const float4*)(XL + (size_t)v * HC + hc);

    // self edge: z = xl[v] + xr[v]; its score is the shift m0
    float z0 = xl4.x + xr4.x, z1 = xl4.y + xr4.y;
    float z2 = xl4.z + xr4.z, z3 = xl4.w + xr4.w;
    float p = fmaxf(z0, 0.2f*z0) * a4.x + fmaxf(z1, 0.2f*z1) * a4.y
            + fmaxf(z2, 0.2f*z2) * a4.z + fmaxf(z3, 0.2f*z3) * a4.w;
    const float m0 = red16(p);

    // self contributes exp(0)=1 exactly once (half 0 only)
    float s  = half ? 0.0f : 1.0f;
    float ax = half ? 0.0f : xl4.x;
    float ay = half ? 0.0f : xl4.y;
    float az = half ? 0.0f : xl4.z;
    float aw = half ? 0.0f : xl4.w;

    int deg = cnt[v];
    if (deg > CAP) deg = CAP;
    int u_l = (lane < deg) ? tbl[v * CAP + lane] : 0;

    const float* __restrict__ XLh = XL + hc;

    // depth-3 pair prefetch (6 edges in flight)
    float4 x0 = make_float4(0,0,0,0), x1 = x0, x2 = x0;
    if (deg > 0) { int u = __shfl(u_l, 0 + half); x0 = *(const float4*)(XLh + (size_t)u * HC); }
    if (deg > 2) { int u = __shfl(u_l, 2 + half); x1 = *(const float4*)(XLh + (size_t)u * HC); }
    if (deg > 4) { int u = __shfl(u_l, 4 + half); x2 = *(const float4*)(XLh + (size_t)u * HC); }

    for (int i = 0; i < deg; i += 2) {
        float4 xc = x0; x0 = x1; x1 = x2;
        if (i + 6 < deg) {
            int u = __shfl(u_l, i + 6 + half);
            x2 = *(const float4*)(XLh + (size_t)u * HC);
        }
        z0 = xc.x + xr4.x; z1 = xc.y + xr4.y;
        z2 = xc.z + xr4.z; z3 = xc.w + xr4.w;
        p = fmaxf(z0, 0.2f*z0) * a4.x + fmaxf(z1, 0.2f*z1) * a4.y
          + fmaxf(z2, 0.2f*z2) * a4.z + fmaxf(z3, 0.2f*z3) * a4.w;
        p = red16(p);
        if (half && (i + 1 >= deg)) p = -1e30f;   // odd-deg tail -> weight 0
        float w = __expf(p - m0);
        s += w;
        ax = fmaf(w, xc.x, ax); ay = fmaf(w, xc.y, ay);
        az = fmaf(w, xc.z, az); aw = fmaf(w, xc.w, aw);
    }

    // merge the two edge streams (same head/channels at lane^32)
    s  += __shfl_xor(s, 32);
    ax += __shfl_xor(ax, 32); ay += __shfl_xor(ay, 32);
    az += __shfl_xor(az, 32); aw += __shfl_xor(aw, 32);

    float inv = 1.0f / (s + 1e-16f);
    ax *= inv; ay *= inv; az *= inv; aw *= inv;

    // mean over heads (head1 sits at lane^16)
    ax += __shfl_xor(ax, 16); ay += __shfl_xor(ay, 16);
    az += __shfl_xor(az, 16); aw += __shfl_xor(aw, 16);
    ax *= 0.5f; ay *= 0.5f; az *= 0.5f; aw *= 0.5f;

    if (lane < 16) {
        const float4 b4 = *(const float4*)(bias + 4 * li);
        ax += b4.x; ay += b4.y; az += b4.z; aw += b4.w;
        if (applyGelu) { ax = gelu_f(ax); ay = gelu_f(ay); az = gelu_f(az); aw = gelu_f(aw); }
        *(float4*)(Y + (size_t)v * 64 + 4 * li) = make_float4(ax, ay, az, aw);
    }
}

extern "C" void kernel_launch(void* const* d_in, const int* in_sizes, int n_in,
                              void* d_out, int out_size, void* d_ws, size_t ws_size,
                              hipStream_t stream) {
    const float* X     = (const float*)d_in[0];
    const int*   edges = (const int*)d_in[1];
    const float* Wl    = (const float*)d_in[2];
    const float* bl    = (const float*)d_in[3];
    const float* Wr    = (const float*)d_in[4];
    const float* br    = (const float*)d_in[5];
    const float* att   = (const float*)d_in[6];
    const float* bias  = (const float*)d_in[7];

    char* ws = (char*)d_ws;
    float* XLb = (float*)ws;                                          // N*128 f32
    float* XRb = (float*)(ws + (size_t)N_NODES * HC * 4);             // N*128 f32
    float* Yb  = (float*)(ws + (size_t)N_NODES * HC * 8);             // N*64 f32
    int*   cnt = (int*)(ws + (size_t)N_NODES * HC * 8 + (size_t)N_NODES * 64 * 4);
    int*   tbl = cnt + N_NODES;                                       // N*CAP ints

    hipMemsetAsync(cnt, 0, N_NODES * sizeof(int), stream);
    scatter_kernel<<<(N_EDGES + 255) / 256, 256, 0, stream>>>(edges, cnt, tbl);

    const int gemm_grid = (N_NODES + 63) / 64;
    const int agg_grid  = (N_NODES * 64 + 255) / 256;

    // layer 0
    gemm_kernel<<<gemm_grid, 256, 0, stream>>>(X, Wl, bl, Wr, br, XLb, XRb);
    aggregate_kernel<<<agg_grid, 256, 0, stream>>>(XLb, XRb, cnt, tbl, att, bias, Yb, 1);
    // layer 1
    gemm_kernel<<<gemm_grid, 256, 0, stream>>>(Yb, Wl + 8192, bl + 128, Wr + 8192, br + 128, XLb, XRb);
    aggregate_kernel<<<agg_grid, 256, 0, stream>>>(XLb, XRb, cnt, tbl, att + 128, bias + 64,
                                                   (float*)d_out, 0);
}

// Round 3
// 386.618 us; speedup vs baseline: 1.3144x; 1.3144x over previous
//
#include <hip/hip_runtime.h>
#include <math.h>

#define N_NODES 100000
#define N_EDGES 800000
#define D_IN    64
#define HC      128   // H*C
#define CAP     48    // max in-degree slots (Poisson(8): P(>48) ~ 0)

// tanh-approx gelu (jax.nn.gelu default approximate=True)
__device__ __forceinline__ float gelu_f(float x) {
    float x3 = x * x * x;
    float y  = 0.7978845608028654f * (x + 0.044715f * x3);
    float t = 1.0f - 2.0f / (__expf(2.0f * y) + 1.0f);
    return 0.5f * x * (1.0f + t);
}

// sum across a 16-lane row via DPP row_ror (pure VALU, no ds_swizzle)
__device__ __forceinline__ float red16(float x) {
    x += __int_as_float(__builtin_amdgcn_mov_dpp(__float_as_int(x), 0x128, 0xF, 0xF, true)); // ror:8
    x += __int_as_float(__builtin_amdgcn_mov_dpp(__float_as_int(x), 0x124, 0xF, 0xF, true)); // ror:4
    x += __int_as_float(__builtin_amdgcn_mov_dpp(__float_as_int(x), 0x122, 0xF, 0xF, true)); // ror:2
    x += __int_as_float(__builtin_amdgcn_mov_dpp(__float_as_int(x), 0x121, 0xF, 0xF, true)); // ror:1
    return x;
}

// ---------------- CSR-by-capacity scatter (once; shared by both layers) ----
__global__ void scatter_kernel(const int* __restrict__ edges,
                               int* __restrict__ cnt, int* __restrict__ tbl) {
    int e = blockIdx.x * blockDim.x + threadIdx.x;
    if (e >= N_EDGES) return;
    int s = edges[e];            // src row
    int d = edges[N_EDGES + e];  // dst row
    int slot = atomicAdd(&cnt[d], 1);
    if (slot < CAP) tbl[d * CAP + slot] = s;
}

// ---------------- xl/xr GEMM as [N,64]@[64,256] register-blocked SGEMM ------
// Block = 64 nodes x 256 out-channels (XL: 0..127 = Wl, XR: 128..255 = Wr).
// LDS: XT[k][n] 16KB (X tile transposed) + WS[k][c] 64KB (both W matrices)
// = 80KB -> 2 blocks/CU. Thread = 8x8 register tile (8 nodes x 8 ch):
// per k-step 4x ds_read_b128 -> 64 independent FMAs (ratio 64:4; X reads are
// 8-fold broadcast, W reads contiguous -> no bank conflicts in loop).
// No scalar loads in the loop: kills the s_load latency serialization that
// pinned rounds 1-2 at VALUBusy 17%.
__global__ __launch_bounds__(256, 2) void gemm_kernel(
    const float* __restrict__ X,
    const float* __restrict__ Wl, const float* __restrict__ bl,
    const float* __restrict__ Wr, const float* __restrict__ br,
    float* __restrict__ XL, float* __restrict__ XR) {
    __shared__ float XT[64 * 64];     // [k][n]
    __shared__ float WS[64 * 256];    // [k][c]; c<128: Wl, c>=128: Wr
    const int t  = threadIdx.x;
    const int n0 = blockIdx.x * 64;

    // stage W: 2048 float4 per matrix, 8 per thread, coalesced; LDS writes
    // are contiguous rows (pure BW, no conflict)
    #pragma unroll
    for (int p = 0; p < 8; ++p) {
        int f  = p * 256 + t;
        int k  = f >> 5;
        int c  = (f & 31) * 4;
        *(float4*)&WS[k * 256 + c]       = *(const float4*)(Wl + (size_t)f * 4);
        *(float4*)&WS[k * 256 + 128 + c] = *(const float4*)(Wr + (size_t)f * 4);
    }
    // stage X transposed: coalesced global reads; scalar LDS writes have a
    // 16-way conflict but only 16 instrs/thread one-time (~2% of loop cost)
    #pragma unroll
    for (int p = 0; p < 4; ++p) {
        int f  = p * 256 + t;
        int n  = f >> 4;
        int kq = f & 15;
        int gn = n0 + n;
        float4 v = make_float4(0.0f, 0.0f, 0.0f, 0.0f);
        if (gn < N_NODES) v = *(const float4*)(X + (size_t)gn * D_IN + 4 * kq);
        XT[(4 * kq + 0) * 64 + n] = v.x;
        XT[(4 * kq + 1) * 64 + n] = v.y;
        XT[(4 * kq + 2) * 64 + n] = v.z;
        XT[(4 * kq + 3) * 64 + n] = v.w;
    }
    __syncthreads();

    const int cg = t & 31;           // channel group: channels cg*8..+7
    const int mg = t >> 5;           // node group: nodes mg*8..+7
    const int c0 = cg * 8;

    const float* bp = (cg < 16) ? (bl + c0) : (br + (c0 - 128));
    const float4 b0 = *(const float4*)bp;
    const float4 b1 = *(const float4*)(bp + 4);

    float acc[8][8];
    #pragma unroll
    for (int m = 0; m < 8; ++m) {
        acc[m][0] = b0.x; acc[m][1] = b0.y; acc[m][2] = b0.z; acc[m][3] = b0.w;
        acc[m][4] = b1.x; acc[m][5] = b1.y; acc[m][6] = b1.z; acc[m][7] = b1.w;
    }

    const float* xq = &XT[mg * 8];
    const float* wq = &WS[c0];
    #pragma unroll 4
    for (int k = 0; k < 64; ++k) {
        float4 xa = *(const float4*)(xq + k * 64);
        float4 xb = *(const float4*)(xq + k * 64 + 4);
        float4 wa = *(const float4*)(wq + k * 256);
        float4 wb = *(const float4*)(wq + k * 256 + 4);
        float xv[8] = {xa.x, xa.y, xa.z, xa.w, xb.x, xb.y, xb.z, xb.w};
        float wv[8] = {wa.x, wa.y, wa.z, wa.w, wb.x, wb.y, wb.z, wb.w};
        #pragma unroll
        for (int m = 0; m < 8; ++m)
            #pragma unroll
            for (int c = 0; c < 8; ++c)
                acc[m][c] = fmaf(xv[m], wv[c], acc[m][c]);
    }

    float* __restrict__ OUT = (cg < 16) ? XL : XR;
    const int cc = (cg < 16) ? c0 : c0 - 128;
    #pragma unroll
    for (int m = 0; m < 8; ++m) {
        int n = n0 + mg * 8 + m;
        if (n < N_NODES) {
            float* o = OUT + (size_t)n * HC + cc;
            *(float4*)o       = make_float4(acc[m][0], acc[m][1], acc[m][2], acc[m][3]);
            *(float4*)(o + 4) = make_float4(acc[m][4], acc[m][5], acc[m][6], acc[m][7]);
        }
    }
}

// ---------------- wave-per-node aggregation: 2 edges/iter, 4 ch/lane --------
// lanes 0-31: edge i, lanes 32-63: edge i+1. Within a 32-lane half:
// lanes 0-15 head0, 16-31 head1; lane li handles channels 4*li..4*li+3.
// Score reduce = 4 DPP row_ror adds (no DS ops). Softmax uses a FIXED shift
// m0 = e_self (same alpha ratios as running-max; e - e_self is O(+-15) here,
// safe in fp32) -> accumulation is associative: 1 exp + 4 fma per half.
__global__ __launch_bounds__(256) void aggregate_kernel(
    const float* __restrict__ XL, const float* __restrict__ XR,
    const int* __restrict__ cnt, const int* __restrict__ tbl,
    const float* __restrict__ att, const float* __restrict__ bias,
    float* __restrict__ Y, int applyGelu) {
    const int v = (blockIdx.x * blockDim.x + threadIdx.x) >> 6;
    const int lane = threadIdx.x & 63;
    if (v >= N_NODES) return;
    const int half = lane >> 5;          // which edge of the pair
    const int li   = lane & 15;
    const int hc   = ((lane >> 4) & 1) * 64 + 4 * li;

    const float4 a4  = *(const float4*)(att + hc);
    const float4 xr4 = *(const float4*)(XR + (size_t)v * HC + hc);
    const float4 xl4 = *(const float4*)(XL + (size_t)v * HC + hc);

    // self edge: z = xl[v] + xr[v]; its score is the shift m0
    float z0 = xl4.x + xr4.x, z1 = xl4.y + xr4.y;
    float z2 = xl4.z + xr4.z, z3 = xl4.w + xr4.w;
    float p = fmaxf(z0, 0.2f*z0) * a4.x + fmaxf(z1, 0.2f*z1) * a4.y
            + fmaxf(z2, 0.2f*z2) * a4.z + fmaxf(z3, 0.2f*z3) * a4.w;
    const float m0 = red16(p);

    // self contributes exp(0)=1 exactly once (half 0 only)
    float s  = half ? 0.0f : 1.0f;
    float ax = half ? 0.0f : xl4.x;
    float ay = half ? 0.0f : xl4.y;
    float az = half ? 0.0f : xl4.z;
    float aw = half ? 0.0f : xl4.w;

    int deg = cnt[v];
    if (deg > CAP) deg = CAP;
    int u_l = (lane < deg) ? tbl[v * CAP + lane] : 0;

    const float* __restrict__ XLh = XL + hc;

    // depth-3 pair prefetch (6 edges in flight)
    float4 x0 = make_float4(0,0,0,0), x1 = x0, x2 = x0;
    if (deg > 0) { int u = __shfl(u_l, 0 + half); x0 = *(const float4*)(XLh + (size_t)u * HC); }
    if (deg > 2) { int u = __shfl(u_l, 2 + half); x1 = *(const float4*)(XLh + (size_t)u * HC); }
    if (deg > 4) { int u = __shfl(u_l, 4 + half); x2 = *(const float4*)(XLh + (size_t)u * HC); }

    for (int i = 0; i < deg; i += 2) {
        float4 xc = x0; x0 = x1; x1 = x2;
        if (i + 6 < deg) {
            int u = __shfl(u_l, i + 6 + half);
            x2 = *(const float4*)(XLh + (size_t)u * HC);
        }
        z0 = xc.x + xr4.x; z1 = xc.y + xr4.y;
        z2 = xc.z + xr4.z; z3 = xc.w + xr4.w;
        p = fmaxf(z0, 0.2f*z0) * a4.x + fmaxf(z1, 0.2f*z1) * a4.y
          + fmaxf(z2, 0.2f*z2) * a4.z + fmaxf(z3, 0.2f*z3) * a4.w;
        p = red16(p);
        if (half && (i + 1 >= deg)) p = -1e30f;   // odd-deg tail -> weight 0
        float w = __expf(p - m0);
        s += w;
        ax = fmaf(w, xc.x, ax); ay = fmaf(w, xc.y, ay);
        az = fmaf(w, xc.z, az); aw = fmaf(w, xc.w, aw);
    }

    // merge the two edge streams (same head/channels at lane^32)
    s  += __shfl_xor(s, 32);
    ax += __shfl_xor(ax, 32); ay += __shfl_xor(ay, 32);
    az += __shfl_xor(az, 32); aw += __shfl_xor(aw, 32);

    float inv = 1.0f / (s + 1e-16f);
    ax *= inv; ay *= inv; az *= inv; aw *= inv;

    // mean over heads (head1 sits at lane^16)
    ax += __shfl_xor(ax, 16); ay += __shfl_xor(ay, 16);
    az += __shfl_xor(az, 16); aw += __shfl_xor(aw, 16);
    ax *= 0.5f; ay *= 0.5f; az *= 0.5f; aw *= 0.5f;

    if (lane < 16) {
        const float4 b4 = *(const float4*)(bias + 4 * li);
        ax += b4.x; ay += b4.y; az += b4.z; aw += b4.w;
        if (applyGelu) { ax = gelu_f(ax); ay = gelu_f(ay); az = gelu_f(az); aw = gelu_f(aw); }
        *(float4*)(Y + (size_t)v * 64 + 4 * li) = make_float4(ax, ay, az, aw);
    }
}

extern "C" void kernel_launch(void* const* d_in, const int* in_sizes, int n_in,
                              void* d_out, int out_size, void* d_ws, size_t ws_size,
                              hipStream_t stream) {
    const float* X     = (const float*)d_in[0];
    const int*   edges = (const int*)d_in[1];
    const float* Wl    = (const float*)d_in[2];
    const float* bl    = (const float*)d_in[3];
    const float* Wr    = (const float*)d_in[4];
    const float* br    = (const float*)d_in[5];
    const float* att   = (const float*)d_in[6];
    const float* bias  = (const float*)d_in[7];

    char* ws = (char*)d_ws;
    float* XLb = (float*)ws;                                          // N*128 f32
    float* XRb = (float*)(ws + (size_t)N_NODES * HC * 4);             // N*128 f32
    float* Yb  = (float*)(ws + (size_t)N_NODES * HC * 8);             // N*64 f32
    int*   cnt = (int*)(ws + (size_t)N_NODES * HC * 8 + (size_t)N_NODES * 64 * 4);
    int*   tbl = cnt + N_NODES;                                       // N*CAP ints

    hipMemsetAsync(cnt, 0, N_NODES * sizeof(int), stream);
    scatter_kernel<<<(N_EDGES + 255) / 256, 256, 0, stream>>>(edges, cnt, tbl);

    const int gemm_grid = (N_NODES + 63) / 64;
    const int agg_grid  = (N_NODES * 64 + 255) / 256;

    // layer 0
    gemm_kernel<<<gemm_grid, 256, 0, stream>>>(X, Wl, bl, Wr, br, XLb, XRb);
    aggregate_kernel<<<agg_grid, 256, 0, stream>>>(XLb, XRb, cnt, tbl, att, bias, Yb, 1);
    // layer 1
    gemm_kernel<<<gemm_grid, 256, 0, stream>>>(Yb, Wl + 8192, bl + 128, Wr + 8192, br + 128, XLb, XRb);
    aggregate_kernel<<<agg_grid, 256, 0, stream>>>(XLb, XRb, cnt, tbl, att + 128, bias + 64,
                                                   (float*)d_out, 0);
}

// Round 4
// 346.573 us; speedup vs baseline: 1.4663x; 1.1155x over previous
//
#include <hip/hip_runtime.h>
#include <math.h>

#define N_NODES 100000
#define N_EDGES 800000
#define D_IN    64
#define HC      128   // H*C
#define CAP     48    // max in-degree slots (Poisson(8): P(>48) ~ 0)

#define GEMM_BLOCKS 1563          // ceil(100000/64)
#define FUSED_BLOCKS (3 * GEMM_BLOCKS)   // 4689: role bid%3==2 -> gemm, else scatter

// tanh-approx gelu (jax.nn.gelu default approximate=True)
__device__ __forceinline__ float gelu_f(float x) {
    float x3 = x * x * x;
    float y  = 0.7978845608028654f * (x + 0.044715f * x3);
    float t = 1.0f - 2.0f / (__expf(2.0f * y) + 1.0f);
    return 0.5f * x * (1.0f + t);
}

// sum across a 16-lane row via DPP row_ror (pure VALU, no ds_swizzle)
__device__ __forceinline__ float red16(float x) {
    x += __int_as_float(__builtin_amdgcn_mov_dpp(__float_as_int(x), 0x128, 0xF, 0xF, true)); // ror:8
    x += __int_as_float(__builtin_amdgcn_mov_dpp(__float_as_int(x), 0x124, 0xF, 0xF, true)); // ror:4
    x += __int_as_float(__builtin_amdgcn_mov_dpp(__float_as_int(x), 0x122, 0xF, 0xF, true)); // ror:2
    x += __int_as_float(__builtin_amdgcn_mov_dpp(__float_as_int(x), 0x121, 0xF, 0xF, true)); // ror:1
    return x;
}

// ---------------- fused GEMM (+ optional scatter role) ----------------------
// GEMM: [N,64]@[64,256] register-blocked SGEMM. Block = 64 nodes; thread =
// 8 nodes x {XL ch 4cg..+3, XR ch 4cg..+3}. W reads span all 32 banks
// (4-deep = data floor; old cg*8 map was 8-16 deep). LDS = XT 17KB + WS 32KB
// (two 32-k stages) = 49KB -> 3 blocks/CU.
// SCATTER role (fused==1, bid%3!=2): 800k random atomicAdd slot allocation.
// Atomic-pipe-bound, ~zero VALU/LDS -> overlaps gemm's VALU work on the same
// CUs instead of costing ~60us serially.
__global__ __launch_bounds__(256, 3) void gemm_scatter_kernel(
    const float* __restrict__ X,
    const float* __restrict__ Wl, const float* __restrict__ bl,
    const float* __restrict__ Wr, const float* __restrict__ br,
    float* __restrict__ XL, float* __restrict__ XR,
    const int* __restrict__ edges, int* __restrict__ cnt, int* __restrict__ tbl,
    int fused) {
    __shared__ float XT[64 * 68];     // [k][n], stride 68 (16B-aligned rows)
    __shared__ float WS[32 * 256];    // [kk][c]; c<128: Wl, c>=128: Wr

    const int t = threadIdx.x;
    int gid;
    if (fused) {
        const int g = blockIdx.x / 3, r = blockIdx.x % 3;
        if (r != 2) {                      // ---- scatter role ----
            const int e = (2 * g + r) * 256 + t;
            if (e < N_EDGES) {
                int s = edges[e];          // src
                int d = edges[N_EDGES + e];// dst
                int slot = atomicAdd(&cnt[d], 1);
                if (slot < CAP) tbl[d * CAP + slot] = s;
            }
            return;
        }
        gid = g;
    } else {
        gid = blockIdx.x;
    }
    const int n0 = gid * 64;

    // stage X transposed: coalesced global reads; stride-68 writes ~8-way
    // conflict, one-time (16 instrs)
    #pragma unroll
    for (int p = 0; p < 4; ++p) {
        int f  = p * 256 + t;
        int n  = f >> 4;
        int kq = f & 15;
        int gn = n0 + n;
        float4 v = make_float4(0.0f, 0.0f, 0.0f, 0.0f);
        if (gn < N_NODES) v = *(const float4*)(X + (size_t)gn * D_IN + 4 * kq);
        XT[(4 * kq + 0) * 68 + n] = v.x;
        XT[(4 * kq + 1) * 68 + n] = v.y;
        XT[(4 * kq + 2) * 68 + n] = v.z;
        XT[(4 * kq + 3) * 68 + n] = v.w;
    }

    const int cg = t & 31;            // channel group: ch 4cg..4cg+3 (XL & XR)
    const int mg = t >> 5;            // node group: nodes mg*8..+7

    const float4 bL = *(const float4*)(bl + 4 * cg);
    const float4 bR = *(const float4*)(br + 4 * cg);
    float acc[8][8];                  // [m][0..3]=XL, [m][4..7]=XR
    #pragma unroll
    for (int m = 0; m < 8; ++m) {
        acc[m][0] = bL.x; acc[m][1] = bL.y; acc[m][2] = bL.z; acc[m][3] = bL.w;
        acc[m][4] = bR.x; acc[m][5] = bR.y; acc[m][6] = bR.z; acc[m][7] = bR.w;
    }

    #pragma unroll 1
    for (int s = 0; s < 2; ++s) {     // two 32-k stages (keeps LDS at 49KB)
        // stage WS[kk][c]: 2048 float4, 8/thread, coalesced; writes span all
        // banks 8-deep
        #pragma unroll
        for (int p = 0; p < 8; ++p) {
            int f  = p * 256 + t;
            int kk = f >> 6;          // 0..31
            int c4 = f & 63;          // float4 idx in 256-ch row
            const float* srcW = (c4 < 32)
                ? (Wl + (size_t)(32 * s + kk) * HC + 4 * c4)
                : (Wr + (size_t)(32 * s + kk) * HC + 4 * (c4 - 32));
            *(float4*)&WS[kk * 256 + 4 * c4] = *(const float4*)srcW;
        }
        __syncthreads();

        const float* xq = &XT[(32 * s) * 68 + 8 * mg];
        #pragma unroll 4
        for (int kk = 0; kk < 32; ++kk) {
            float4 xa  = *(const float4*)(xq + kk * 68);       // 32-fold bcast
            float4 xb  = *(const float4*)(xq + kk * 68 + 4);
            float4 wl4 = *(const float4*)(&WS[kk * 256 + 4 * cg]);       // full banks
            float4 wr4 = *(const float4*)(&WS[kk * 256 + 128 + 4 * cg]); // full banks
            float xv[8] = {xa.x, xa.y, xa.z, xa.w, xb.x, xb.y, xb.z, xb.w};
            #pragma unroll
            for (int m = 0; m < 8; ++m) {
                acc[m][0] = fmaf(xv[m], wl4.x, acc[m][0]);
                acc[m][1] = fmaf(xv[m], wl4.y, acc[m][1]);
                acc[m][2] = fmaf(xv[m], wl4.z, acc[m][2]);
                acc[m][3] = fmaf(xv[m], wl4.w, acc[m][3]);
                acc[m][4] = fmaf(xv[m], wr4.x, acc[m][4]);
                acc[m][5] = fmaf(xv[m], wr4.y, acc[m][5]);
                acc[m][6] = fmaf(xv[m], wr4.z, acc[m][6]);
                acc[m][7] = fmaf(xv[m], wr4.w, acc[m][7]);
            }
        }
        __syncthreads();
    }

    #pragma unroll
    for (int m = 0; m < 8; ++m) {
        int n = n0 + mg * 8 + m;
        if (n < N_NODES) {
            *(float4*)(XL + (size_t)n * HC + 4 * cg) =
                make_float4(acc[m][0], acc[m][1], acc[m][2], acc[m][3]);
            *(float4*)(XR + (size_t)n * HC + 4 * cg) =
                make_float4(acc[m][4], acc[m][5], acc[m][6], acc[m][7]);
        }
    }
}

// ---------------- wave-per-node aggregation: 2 edges/iter, 4 ch/lane --------
// lanes 0-31: edge i, lanes 32-63: edge i+1. Within a 32-lane half:
// lanes 0-15 head0, 16-31 head1; lane li handles channels 4*li..4*li+3.
// Score reduce = 4 DPP row_ror adds. Fixed shift m0 = e_self (associative
// softmax). att pre-scaled by log2(e) -> exp2f (v_exp direct, saves a mul).
__global__ __launch_bounds__(256) void aggregate_kernel(
    const float* __restrict__ XL, const float* __restrict__ XR,
    const int* __restrict__ cnt, const int* __restrict__ tbl,
    const float* __restrict__ att, const float* __restrict__ bias,
    float* __restrict__ Y, int applyGelu) {
    const int v = (blockIdx.x * blockDim.x + threadIdx.x) >> 6;
    const int lane = threadIdx.x & 63;
    if (v >= N_NODES) return;
    const int half = lane >> 5;          // which edge of the pair
    const int li   = lane & 15;
    const int hc   = ((lane >> 4) & 1) * 64 + 4 * li;

    float4 a4  = *(const float4*)(att + hc);
    a4.x *= 1.44269504f; a4.y *= 1.44269504f;    // log2(e): scores in log2
    a4.z *= 1.44269504f; a4.w *= 1.44269504f;    // domain, softmax unchanged
    const float4 xr4 = *(const float4*)(XR + (size_t)v * HC + hc);
    const float4 xl4 = *(const float4*)(XL + (size_t)v * HC + hc);

    // self edge: z = xl[v] + xr[v]; its score is the shift m0
    float z0 = xl4.x + xr4.x, z1 = xl4.y + xr4.y;
    float z2 = xl4.z + xr4.z, z3 = xl4.w + xr4.w;
    float p = fmaxf(z0, 0.2f*z0) * a4.x + fmaxf(z1, 0.2f*z1) * a4.y
            + fmaxf(z2, 0.2f*z2) * a4.z + fmaxf(z3, 0.2f*z3) * a4.w;
    const float m0 = red16(p);

    // self contributes exp(0)=1 exactly once (half 0 only)
    float s  = half ? 0.0f : 1.0f;
    float ax = half ? 0.0f : xl4.x;
    float ay = half ? 0.0f : xl4.y;
    float az = half ? 0.0f : xl4.z;
    float aw = half ? 0.0f : xl4.w;

    int deg = cnt[v];
    if (deg > CAP) deg = CAP;
    int u_l = (lane < deg) ? tbl[v * CAP + lane] : 0;

    const float* __restrict__ XLh = XL + hc;

    // depth-3 pair prefetch (6 edges in flight)
    float4 x0 = make_float4(0,0,0,0), x1 = x0, x2 = x0;
    if (deg > 0) { int u = __shfl(u_l, 0 + half); x0 = *(const float4*)(XLh + (size_t)u * HC); }
    if (deg > 2) { int u = __shfl(u_l, 2 + half); x1 = *(const float4*)(XLh + (size_t)u * HC); }
    if (deg > 4) { int u = __shfl(u_l, 4 + half); x2 = *(const float4*)(XLh + (size_t)u * HC); }

    for (int i = 0; i < deg; i += 2) {
        float4 xc = x0; x0 = x1; x1 = x2;
        if (i + 6 < deg) {
            int u = __shfl(u_l, i + 6 + half);
            x2 = *(const float4*)(XLh + (size_t)u * HC);
        }
        z0 = xc.x + xr4.x; z1 = xc.y + xr4.y;
        z2 = xc.z + xr4.z; z3 = xc.w + xr4.w;
        p = fmaxf(z0, 0.2f*z0) * a4.x + fmaxf(z1, 0.2f*z1) * a4.y
          + fmaxf(z2, 0.2f*z2) * a4.z + fmaxf(z3, 0.2f*z3) * a4.w;
        p = red16(p);
        if (half && (i + 1 >= deg)) p = -1e30f;   // odd-deg tail -> weight 0
        float w = exp2f(p - m0);
        s += w;
        ax = fmaf(w, xc.x, ax); ay = fmaf(w, xc.y, ay);
        az = fmaf(w, xc.z, az); aw = fmaf(w, xc.w, aw);
    }

    // merge the two edge streams (same head/channels at lane^32)
    s  += __shfl_xor(s, 32);
    ax += __shfl_xor(ax, 32); ay += __shfl_xor(ay, 32);
    az += __shfl_xor(az, 32); aw += __shfl_xor(aw, 32);

    float inv = 1.0f / (s + 1e-16f);
    ax *= inv; ay *= inv; az *= inv; aw *= inv;

    // mean over heads (head1 sits at lane^16)
    ax += __shfl_xor(ax, 16); ay += __shfl_xor(ay, 16);
    az += __shfl_xor(az, 16); aw += __shfl_xor(aw, 16);
    ax *= 0.5f; ay *= 0.5f; az *= 0.5f; aw *= 0.5f;

    if (lane < 16) {
        const float4 b4 = *(const float4*)(bias + 4 * li);
        ax += b4.x; ay += b4.y; az += b4.z; aw += b4.w;
        if (applyGelu) { ax = gelu_f(ax); ay = gelu_f(ay); az = gelu_f(az); aw = gelu_f(aw); }
        *(float4*)(Y + (size_t)v * 64 + 4 * li) = make_float4(ax, ay, az, aw);
    }
}

extern "C" void kernel_launch(void* const* d_in, const int* in_sizes, int n_in,
                              void* d_out, int out_size, void* d_ws, size_t ws_size,
                              hipStream_t stream) {
    const float* X     = (const float*)d_in[0];
    const int*   edges = (const int*)d_in[1];
    const float* Wl    = (const float*)d_in[2];
    const float* bl    = (const float*)d_in[3];
    const float* Wr    = (const float*)d_in[4];
    const float* br    = (const float*)d_in[5];
    const float* att   = (const float*)d_in[6];
    const float* bias  = (const float*)d_in[7];

    char* ws = (char*)d_ws;
    float* XLb = (float*)ws;                                          // N*128 f32
    float* XRb = (float*)(ws + (size_t)N_NODES * HC * 4);             // N*128 f32
    float* Yb  = (float*)(ws + (size_t)N_NODES * HC * 8);             // N*64 f32
    int*   cnt = (int*)(ws + (size_t)N_NODES * HC * 8 + (size_t)N_NODES * 64 * 4);
    int*   tbl = cnt + N_NODES;                                       // N*CAP ints

    hipMemsetAsync(cnt, 0, N_NODES * sizeof(int), stream);

    const int agg_grid = (N_NODES * 64 + 255) / 256;

    // layer 0: gemm + scatter fused (disjoint pipes: VALU/LDS vs atomics)
    gemm_scatter_kernel<<<FUSED_BLOCKS, 256, 0, stream>>>(
        X, Wl, bl, Wr, br, XLb, XRb, edges, cnt, tbl, 1);
    aggregate_kernel<<<agg_grid, 256, 0, stream>>>(XLb, XRb, cnt, tbl, att, bias, Yb, 1);
    // layer 1
    gemm_scatter_kernel<<<GEMM_BLOCKS, 256, 0, stream>>>(
        Yb, Wl + 8192, bl + 128, Wr + 8192, br + 128, XLb, XRb, edges, cnt, tbl, 0);
    aggregate_kernel<<<agg_grid, 256, 0, stream>>>(XLb, XRb, cnt, tbl, att + 128, bias + 64,
                                                   (float*)d_out, 0);
}